// Round 13
// baseline (106.832 us; speedup 1.0000x reference)
//
#include <hip/hip_runtime.h>
#include <math.h>

#define NFFT   2048
#define M2     1024
#define LOG2N  11
#define BB     8
#define WW     32
#define MM     16
#define NLAYER 4
#define AST    1032      // row stride (float2) for alpha / G half-spectra

// Padded LDS index (element-granular) for 1024-pt FFT arrays
#define PAD(i) ((i) + ((i) >> 5))
#define PADDED_M (M2 + (M2 >> 5))   // 1056

// ---------- fast gelu (exact-erf form, A&S 7.1.26, |err| <= 1.5e-7) ----------
__device__ __forceinline__ float gelu_f(float v) {
    float ax = fabsf(v) * 0.70710678118654752440f;
    float t  = __builtin_amdgcn_rcpf(fmaf(0.3275911f, ax, 1.0f));
    float s  = fmaf(1.061405429f, t, -1.453152027f);
    s = fmaf(s, t, 1.421413741f);
    s = fmaf(s, t, -0.284496736f);
    s = fmaf(s, t, 0.254829592f);
    s = s * t;
    float e  = __expf(-ax * ax);
    float er = fmaf(-s, e, 1.0f);          // erf(|v|/sqrt2)
    er = copysignf(er, v);
    return 0.5f * v * (1.0f + er);
}

// ---------- complex helpers ----------
__device__ __forceinline__ float2 cadd(float2 a, float2 b) { return make_float2(a.x + b.x, a.y + b.y); }
__device__ __forceinline__ float2 csub(float2 a, float2 b) { return make_float2(a.x - b.x, a.y - b.y); }
__device__ __forceinline__ float2 cmul(float2 a, float2 b) {
    return make_float2(fmaf(a.x, b.x, -a.y * b.y), fmaf(a.x, b.y, a.y * b.x));
}
template<int S> __device__ __forceinline__ float2 caddi(float2 a, float2 b) {
    return (S > 0) ? make_float2(a.x - b.y, a.y + b.x) : make_float2(a.x + b.y, a.y - b.x);
}
template<int S> __device__ __forceinline__ float2 csubi(float2 a, float2 b) {
    return (S > 0) ? make_float2(a.x + b.y, a.y - b.x) : make_float2(a.x - b.y, a.y + b.x);
}

template<int S> __device__ __forceinline__ void dft4(float2* a) {
    float2 t0 = cadd(a[0], a[2]), t1 = csub(a[0], a[2]);
    float2 t2 = cadd(a[1], a[3]), t3 = csub(a[1], a[3]);
    a[0] = cadd(t0, t2);
    a[2] = csub(t0, t2);
    a[1] = caddi<S>(t1, t3);
    a[3] = csubi<S>(t1, t3);
}

// ---------- Stockham radix-4 pass on float2 LDS, reg twiddle w1 ----------
// w1f is the FORWARD twiddle (cos, -sin) for this thread's s; S>0 conjugates.
template<int LS, int S>
__device__ __forceinline__ void pass_cx(const float2* src, float2* dst, int t, float2 w1f) {
    float2 a[4];
    #pragma unroll
    for (int r = 0; r < 4; ++r) a[r] = src[PAD(t + r * 256)];
    if (LS > 1) {
        float2 w1 = (S > 0) ? make_float2(w1f.x, -w1f.y) : w1f;
        float2 w2 = cmul(w1, w1);
        float2 w3 = cmul(w2, w1);
        a[1] = cmul(a[1], w1);
        a[2] = cmul(a[2], w2);
        a[3] = cmul(a[3], w3);
    }
    dft4<S>(a);
    int s = t & (LS - 1);
    int base = (t / LS) * (4 * LS) + s;
    #pragma unroll
    for (int r = 0; r < 4; ++r) dst[PAD(base + r * LS)] = a[r];
}

// Forward twiddles for the 4 twiddled passes, computed once per thread (t<256).
struct Tw { float2 t4, t16, t64, t256; };
__device__ __forceinline__ Tw make_tw(int t) {
    Tw w;
    float sn, cs;
    const float c0 = 6.2831853071795864769f;
    __sincosf(c0 * (float)(t & 3)   * (1.0f / 16.0f),   &sn, &cs); w.t4   = make_float2(cs, -sn);
    __sincosf(c0 * (float)(t & 15)  * (1.0f / 64.0f),   &sn, &cs); w.t16  = make_float2(cs, -sn);
    __sincosf(c0 * (float)(t & 63)  * (1.0f / 256.0f),  &sn, &cs); w.t64  = make_float2(cs, -sn);
    __sincosf(c0 * (float)(t & 255) * (1.0f / 1024.0f), &sn, &cs); w.t256 = make_float2(cs, -sn);
    return w;
}

// 1024-pt FFT: input natural order in A, output in B. act = (t < 256).
// Caller must __syncthreads() before calling.
template<int S>
__device__ __forceinline__ void fft1024_cx(float2* A, float2* B, int t, bool act, const Tw& w) {
    if (act) pass_cx<1,   S>(A, B, t, make_float2(1.0f, 0.0f));
    __syncthreads();
    if (act) pass_cx<4,   S>(B, A, t, w.t4);
    __syncthreads();
    if (act) pass_cx<16,  S>(A, B, t, w.t16);
    __syncthreads();
    if (act) pass_cx<64,  S>(B, A, t, w.t64);
    __syncthreads();
    if (act) pass_cx<256, S>(A, B, t, w.t256);
    __syncthreads();
}

// ---------- genG unit: one (l,o,i), executed by one wave (lane = 0..63) ------
// Each lane owns 16 bins k = lane + 64j. Modes outer, bins inner; imag
// accumulator defers the *omega to the end. Lane 0 handles Nyquist + DC.
__device__ __forceinline__ void genG_unit(
    int l, int o, int i, int lane, float fscale,
    const float* __restrict__ pole_re, const float* __restrict__ pole_im,
    const float* __restrict__ res_re,  const float* __restrict__ res_im,
    const float* __restrict__ spec_re, const float* __restrict__ spec_im,
    const float* __restrict__ conv_w,  float2* __restrict__ G)
{
    int pb = ((l * WW + i) * WW + o) * MM;
    float cw = conv_w[(l * WW + o) * WW + i];
    float w2r[16];
    float2 acc[16];
    #pragma unroll
    for (int j = 0; j < 16; ++j) {
        float wv = fscale * (float)(lane + 64 * j);
        w2r[j] = wv * wv;
        acc[j] = make_float2(cw, 0.0f);
    }
    #pragma unroll
    for (int mq = 0; mq < 4; ++mq) {
        float4 P_re = *(const float4*)&pole_re[pb + 4 * mq];
        float4 P_im = *(const float4*)&pole_im[pb + 4 * mq];
        float4 R_re = *(const float4*)&res_re [pb + 4 * mq];
        float4 R_im = *(const float4*)&res_im [pb + 4 * mq];
        #pragma unroll
        for (int mm = 0; mm < 4; ++mm) {
            float Rp = (&P_re.x)[mm], Ip = (&P_im.x)[mm];
            float Rr = (&R_re.x)[mm], Ir = (&R_im.x)[mm];
            float b   = fmaf(Rr, Rp, Ir * Ip);      // Re(r * conj(p))
            float c   = fmaf(Rp, Rp, Ip * Ip);      // |p|^2
            float dd  = 2.0f * Rp;
            float dd2 = dd * dd;
            float add = Rr * dd;
            float bdd = b * dd;
            #pragma unroll
            for (int j = 0; j < 16; ++j) {
                float uu  = c - w2r[j];
                float inv = __builtin_amdgcn_rcpf(fmaf(dd2, w2r[j], uu * uu));
                acc[j].x = fmaf(fmaf(add, w2r[j], b * uu), -inv, acc[j].x);
                acc[j].y = fmaf(fmaf(Rr, uu, -bdd), inv, acc[j].y);  // *wv deferred
            }
        }
    }
    #pragma unroll
    for (int j = 0; j < 16; ++j)
        acc[j].y *= fscale * (float)(lane + 64 * j);
    if (lane < MM) {               // spectral-conv fold: bins k = lane < 16
        if (lane) {
            acc[0].x += spec_re[pb + lane];
            acc[0].y += spec_im[pb + lane];
        } else {
            acc[0].x += spec_re[pb];   // DC stays real
        }
    }
    float2* grow = G + (size_t)((l * WW + o) * WW + i) * AST;
    #pragma unroll
    for (int j = 0; j < 16; ++j) grow[lane + 64 * j] = acc[j];
    if (lane == 0) {               // Nyquist: Re(H(w_nyq)), w negative
        float wn = -fscale * (float)M2;
        float accn = cw;
        #pragma unroll
        for (int mq = 0; mq < 4; ++mq) {
            float4 P_re = *(const float4*)&pole_re[pb + 4 * mq];
            float4 P_im = *(const float4*)&pole_im[pb + 4 * mq];
            float4 R_re = *(const float4*)&res_re [pb + 4 * mq];
            float4 R_im = *(const float4*)&res_im [pb + 4 * mq];
            #pragma unroll
            for (int mm = 0; mm < 4; ++mm) {
                float Rp = (&P_re.x)[mm], Ip = (&P_im.x)[mm];
                float Rr = (&R_re.x)[mm], Ir = (&R_im.x)[mm];
                float e   = wn - Ip;
                float num = fmaf(Ir, e, -(Rr * Rp));
                float den = fmaf(e, e, Rp * Rp);
                accn += num * __builtin_amdgcn_rcpf(den);
            }
        }
        grow[M2] = make_float2(accn, 0.0f);
    }
}

// ---------- K0: genG layer 0 (blocks 0..255) + fc0+rfft (blocks 256..511) ----
__global__ __launch_bounds__(256) void k_genG_fc0(
    const float* __restrict__ pole_re, const float* __restrict__ pole_im,
    const float* __restrict__ res_re,  const float* __restrict__ res_im,
    const float* __restrict__ spec_re, const float* __restrict__ spec_im,
    const float* __restrict__ conv_w,  const float* __restrict__ tgrid,
    const float* __restrict__ x,       const float* __restrict__ fc0_w,
    const float* __restrict__ fc0_b,
    float2* __restrict__ G, float2* __restrict__ alpha)
{
    __shared__ float2 Acx[PADDED_M], Bcx[PADDED_M];
    int t = threadIdx.x;
    int blk = blockIdx.x;
    float dt = tgrid[1] - tgrid[0];
    float fscale = 6.2831853071795864769f / ((float)NFFT * dt);

    if (blk < WW * WW / 4) {
        // ---- genG layer 0: one (o,i) unit per wave, 4 waves/block ----
        int u = blk * 4 + (t >> 6);          // 0..1023
        genG_unit(0, u >> 5, u & 31, t & 63, fscale,
                  pole_re, pole_im, res_re, res_im, spec_re, spec_im, conv_w, G);
    } else {
        // ---- fc0 + rfft path ----
        int row = blk - WW * WW / 4;         // b*32 + w
        int b = row >> 5, w = row & 31;
        float w0 = fc0_w[2 * w], w1 = fc0_w[2 * w + 1], b0 = fc0_b[w];
        Tw tw = make_tw(t);
        const float2* x2 = (const float2*)(x + (size_t)b * NFFT);
        #pragma unroll
        for (int j = 0; j < 4; ++j) {
            int n = t + j * 256;
            float2 xv = x2[n];
            float g0 = (float)(2 * n)     * (1.0f / 2047.0f);
            float g1 = (float)(2 * n + 1) * (1.0f / 2047.0f);
            float v0 = gelu_f(fmaf(w0, xv.x, fmaf(w1, g0, b0)));
            float v1 = gelu_f(fmaf(w0, xv.y, fmaf(w1, g1, b0)));
            Acx[PAD(n)] = make_float2(v0, v1);   // z[n] = h[2n] + i h[2n+1]
        }
        __syncthreads();
        fft1024_cx<-1>(Acx, Bcx, t, true, tw);
        float2* arow = alpha + (size_t)row * AST;
        #pragma unroll
        for (int j = 0; j < 4; ++j) {
            int k  = t + j * 256;
            int mk = (M2 - k) & (M2 - 1);
            float2 Zk  = Bcx[PAD(k)];
            float2 Zmk = Bcx[PAD(mk)];
            float2 A  = make_float2(0.5f * (Zk.x + Zmk.x), 0.5f * (Zk.y - Zmk.y));
            float2 Bv = make_float2(0.5f * (Zk.y + Zmk.y), -0.5f * (Zk.x - Zmk.x));
            float ph = (3.1415926535897932385f / (float)M2) * (float)k;
            float sn, cs;
            __sincosf(ph, &sn, &cs);
            float2 e = make_float2(cs, -sn);           // e^{-i*2pi*k/N}
            float2 X = cadd(A, cmul(Bv, e));
            arow[k] = X;
            if (k == 0) arow[M2] = make_float2(A.x - Bv.x, 0.0f);
        }
    }
}

// ---------- K_layer: einsum over i + irfft + gelu + (rfft | store h) ----------
// Blocks 0..255: apply for row (b,o), 512 threads (r11-proven body).
// Blocks 256..383 (when genL < NLAYER): genG rider for layer genL —
// 8 waves x 1 unit each; written G is consumed only by the NEXT launch.
template<bool LAST>
__global__ __launch_bounds__(512) void k_apply_fft(
    const float2* __restrict__ alpha, const float2* __restrict__ G,
    const float* __restrict__ conv_b, float2* __restrict__ alpha_next,
    float2* __restrict__ hout, int layer,
    const float* __restrict__ pole_re, const float* __restrict__ pole_im,
    const float* __restrict__ res_re,  const float* __restrict__ res_im,
    const float* __restrict__ spec_re, const float* __restrict__ spec_im,
    const float* __restrict__ conv_w,  const float* __restrict__ tgrid,
    float2* __restrict__ Gout, int genL)
{
    __shared__ __align__(16) float2 Ycx[M2 + 2];
    __shared__ float2 Acx[PADDED_M], Bcx[PADDED_M];
    int t = threadIdx.x;
    int blk = blockIdx.x;

    if (blk >= BB * WW) {
        // ---- genG rider: layer genL, unit per wave ----
        float dt = tgrid[1] - tgrid[0];
        float fscale = 6.2831853071795864769f / ((float)NFFT * dt);
        int u = (blk - BB * WW) * 8 + (t >> 6);     // 0..1023
        genG_unit(genL, u >> 5, u & 31, t & 63, fscale,
                  pole_re, pole_im, res_re, res_im, spec_re, spec_im, conv_w, Gout);
        return;
    }

    int row = blk;                   // b*32 + o
    int b = row >> 5, o = row & 31;
    const float2* abase = alpha + (size_t)(b * WW) * AST;
    const float2* gbase = G + (size_t)((layer * WW + o) * WW) * AST;
    Tw tw;
    if (t < 256) tw = make_tw(t);

    // einsum: thread t owns bins 2t, 2t+1 -> float4 loads (16B)
    float2 acc0 = make_float2(0.0f, 0.0f);
    float2 acc1 = make_float2(0.0f, 0.0f);
    #pragma unroll 4
    for (int i = 0; i < 32; ++i) {
        const float4* ar = (const float4*)(abase + (size_t)i * AST);
        const float4* gr = (const float4*)(gbase + (size_t)i * AST);
        float4 av = ar[t];
        float4 gv = gr[t];
        acc0.x = fmaf(av.x, gv.x, fmaf(-av.y, gv.y, acc0.x));
        acc0.y = fmaf(av.x, gv.y, fmaf( av.y, gv.x, acc0.y));
        acc1.x = fmaf(av.z, gv.z, fmaf(-av.w, gv.w, acc1.x));
        acc1.y = fmaf(av.z, gv.w, fmaf( av.w, gv.z, acc1.y));
    }
    // Nyquist: real dot over i, wave-0 shuffle reduce
    if (t < 64) {
        float p = 0.0f;
        if (t < 32)
            p = abase[(size_t)t * AST + M2].x * gbase[(size_t)t * AST + M2].x;
        #pragma unroll
        for (int off = 16; off >= 1; off >>= 1) p += __shfl_xor(p, off);
        if (t == 0) Ycx[M2] = make_float2(p, 0.0f);
    }
    if (t == 0) acc0.x += (float)NFFT * conv_b[layer * WW + o];
    ((float4*)Ycx)[t] = make_float4(acc0.x, acc0.y, acc1.x, acc1.y);
    __syncthreads();

    // irfft pack: Z[k] = A + iB from X[k], X[M2-k]
    #pragma unroll
    for (int j = 0; j < 2; ++j) {
        int k = t + j * 512;
        float2 Xk = Ycx[k];
        float2 Xm = Ycx[M2 - k];
        float2 A = make_float2(0.5f * (Xk.x + Xm.x), 0.5f * (Xk.y - Xm.y));
        float2 u = make_float2(Xk.x - Xm.x, Xk.y + Xm.y);
        float ph = (3.1415926535897932385f / (float)M2) * (float)k;
        float sn, cs;
        __sincosf(ph, &sn, &cs);
        float2 e = make_float2(cs, sn);            // e^{+i*2pi*k/N}
        float2 Bv = cmul(u, e);
        Acx[PAD(k)] = make_float2(A.x - 0.5f * Bv.y, A.y + 0.5f * Bv.x);
    }
    __syncthreads();
    fft1024_cx<1>(Acx, Bcx, t, t < 256, tw);      // inverse -> B
    const float invM = 1.0f / (float)M2;
    if (LAST) {
        #pragma unroll
        for (int j = 0; j < 2; ++j) {
            int n = t + j * 512;
            float2 z = Bcx[PAD(n)];
            hout[(size_t)row * M2 + n] = make_float2(gelu_f(z.x * invM), gelu_f(z.y * invM));
        }
    } else {
        #pragma unroll
        for (int j = 0; j < 2; ++j) {
            int n = t + j * 512;
            float2 z = Bcx[PAD(n)];
            Acx[PAD(n)] = make_float2(gelu_f(z.x * invM), gelu_f(z.y * invM));
        }
        __syncthreads();
        fft1024_cx<-1>(Acx, Bcx, t, t < 256, tw);
        float2* arow = alpha_next + (size_t)row * AST;
        #pragma unroll
        for (int j = 0; j < 2; ++j) {
            int k  = t + j * 512;
            int mk = (M2 - k) & (M2 - 1);
            float2 Zk  = Bcx[PAD(k)];
            float2 Zmk = Bcx[PAD(mk)];
            float2 A  = make_float2(0.5f * (Zk.x + Zmk.x), 0.5f * (Zk.y - Zmk.y));
            float2 Bv = make_float2(0.5f * (Zk.y + Zmk.y), -0.5f * (Zk.x - Zmk.x));
            float ph = (3.1415926535897932385f / (float)M2) * (float)k;
            float sn, cs;
            __sincosf(ph, &sn, &cs);
            float2 e = make_float2(cs, -sn);       // e^{-i*2pi*k/N}
            float2 X = cadd(A, cmul(Bv, e));
            arow[k] = X;
            if (k == 0) arow[M2] = make_float2(A.x - Bv.x, 0.0f);
        }
    }
}

// ---------- K5: head ----------
__global__ __launch_bounds__(256) void k_head(
    const float* __restrict__ h, const float* __restrict__ fc1_w,
    const float* __restrict__ fc1_b, const float* __restrict__ fc2_w,
    const float* __restrict__ fc2_b, float* __restrict__ out)
{
    __shared__ float s_w1[128 * 32];
    __shared__ float s_b1[128];
    __shared__ float s_w2[128];
    __shared__ float s_part[4][64];
    int t = threadIdx.x;
    for (int j = t; j < 128 * 32; j += 256) s_w1[j] = fc1_w[j];
    if (t < 128) { s_b1[t] = fc1_b[t]; s_w2[t] = fc2_w[t]; }
    __syncthreads();
    int wv  = t >> 6;                       // wave id = n-group
    int ln  = t & 63;
    int pos = blockIdx.x * 64 + ln;         // b*2048 + l
    int b = pos >> LOG2N, l = pos & (NFFT - 1);
    float hreg[32];
    #pragma unroll
    for (int w = 0; w < 32; ++w) hreg[w] = h[(b * WW + w) * NFFT + l];
    float acc = 0.0f;
    int n0 = wv * 32;
    for (int n = n0; n < n0 + 32; ++n) {
        float a = s_b1[n];
        #pragma unroll
        for (int w = 0; w < 32; w += 4) {
            float4 ww = *(const float4*)&s_w1[n * 32 + w];
            a = fmaf(ww.x, hreg[w],     a);
            a = fmaf(ww.y, hreg[w + 1], a);
            a = fmaf(ww.z, hreg[w + 2], a);
            a = fmaf(ww.w, hreg[w + 3], a);
        }
        acc = fmaf(s_w2[n], gelu_f(a), acc);
    }
    s_part[wv][ln] = acc;
    __syncthreads();
    if (t < 64) {
        float r = s_part[0][t] + s_part[1][t] + s_part[2][t] + s_part[3][t] + fc2_b[0];
        out[blockIdx.x * 64 + t] = r;
    }
}

extern "C" void kernel_launch(void* const* d_in, const int* in_sizes, int n_in,
                              void* d_out, int out_size, void* d_ws, size_t ws_size,
                              hipStream_t stream)
{
    const float* x       = (const float*)d_in[0];
    const float* tg      = (const float*)d_in[1];
    const float* fc0_w   = (const float*)d_in[2];
    const float* fc0_b   = (const float*)d_in[3];
    const float* pole_re = (const float*)d_in[4];
    const float* pole_im = (const float*)d_in[5];
    const float* res_re  = (const float*)d_in[6];
    const float* res_im  = (const float*)d_in[7];
    const float* spec_re = (const float*)d_in[8];
    const float* spec_im = (const float*)d_in[9];
    const float* conv_w  = (const float*)d_in[10];
    const float* conv_b  = (const float*)d_in[11];
    const float* fc1_w   = (const float*)d_in[12];
    const float* fc1_b   = (const float*)d_in[13];
    const float* fc2_w   = (const float*)d_in[14];
    const float* fc2_b   = (const float*)d_in[15];
    float* out = (float*)d_out;

    char* ws = (char*)d_ws;
    const size_t plane = (size_t)(BB * WW) * AST * sizeof(float2);   // 2.11 MiB
    float2* alphaA = (float2*)ws;
    float2* alphaB = (float2*)(ws + plane);
    float2* hbuf   = (float2*)(ws + 2 * plane);                      // 2 MiB
    float2* Gbuf   = (float2*)(ws + 3 * plane);

    // K0: genG layer 0 (256 blocks) + fc0+rfft (256 blocks)
    hipLaunchKernelGGL(k_genG_fc0, dim3(WW * WW / 4 + BB * WW), dim3(256), 0, stream,
                       pole_re, pole_im, res_re, res_im, spec_re, spec_im,
                       conv_w, tg, x, fc0_w, fc0_b, Gbuf, alphaA);
    float2* acur = alphaA;
    float2* anxt = alphaB;
    for (int layer = 0; layer < NLAYER; ++layer) {
        int genL = layer + 1;
        int grid = BB * WW + ((genL < NLAYER) ? 128 : 0);   // + genG rider blocks
        if (layer < NLAYER - 1)
            hipLaunchKernelGGL((k_apply_fft<false>), dim3(grid), dim3(512), 0, stream,
                               acur, Gbuf, conv_b, anxt, (float2*)nullptr, layer,
                               pole_re, pole_im, res_re, res_im, spec_re, spec_im,
                               conv_w, tg, Gbuf, genL);
        else
            hipLaunchKernelGGL((k_apply_fft<true>), dim3(grid), dim3(512), 0, stream,
                               acur, Gbuf, conv_b, (float2*)nullptr, hbuf, layer,
                               pole_re, pole_im, res_re, res_im, spec_re, spec_im,
                               conv_w, tg, Gbuf, genL);
        float2* tmp = acur; acur = anxt; anxt = tmp;
    }
    hipLaunchKernelGGL(k_head, dim3(BB * NFFT / 64), dim3(256), 0, stream,
                       (const float*)hbuf, fc1_w, fc1_b, fc2_w, fc2_b, out);
}

// Round 14
// 90.986 us; speedup vs baseline: 1.1742x; 1.1742x over previous
//
#include <hip/hip_runtime.h>
#include <math.h>

#define NFFT   2048
#define M2     1024
#define LOG2N  11
#define BB     8
#define WW     32
#define MM     16
#define NLAYER 4
#define AST    1032      // row stride (float2) for alpha / G half-spectra

// Padded LDS index (element-granular) for 1024-pt FFT arrays
#define PAD(i) ((i) + ((i) >> 5))
#define PADDED_M (M2 + (M2 >> 5))   // 1056

// ---------- fast gelu (exact-erf form, A&S 7.1.26, |err| <= 1.5e-7) ----------
__device__ __forceinline__ float gelu_f(float v) {
    float ax = fabsf(v) * 0.70710678118654752440f;
    float t  = __builtin_amdgcn_rcpf(fmaf(0.3275911f, ax, 1.0f));
    float s  = fmaf(1.061405429f, t, -1.453152027f);
    s = fmaf(s, t, 1.421413741f);
    s = fmaf(s, t, -0.284496736f);
    s = fmaf(s, t, 0.254829592f);
    s = s * t;
    float e  = __expf(-ax * ax);
    float er = fmaf(-s, e, 1.0f);          // erf(|v|/sqrt2)
    er = copysignf(er, v);
    return 0.5f * v * (1.0f + er);
}

// ---------- complex helpers ----------
__device__ __forceinline__ float2 cadd(float2 a, float2 b) { return make_float2(a.x + b.x, a.y + b.y); }
__device__ __forceinline__ float2 csub(float2 a, float2 b) { return make_float2(a.x - b.x, a.y - b.y); }
__device__ __forceinline__ float2 cmul(float2 a, float2 b) {
    return make_float2(fmaf(a.x, b.x, -a.y * b.y), fmaf(a.x, b.y, a.y * b.x));
}
template<int S> __device__ __forceinline__ float2 caddi(float2 a, float2 b) {
    return (S > 0) ? make_float2(a.x - b.y, a.y + b.x) : make_float2(a.x + b.y, a.y - b.x);
}
template<int S> __device__ __forceinline__ float2 csubi(float2 a, float2 b) {
    return (S > 0) ? make_float2(a.x + b.y, a.y - b.x) : make_float2(a.x - b.y, a.y + b.x);
}

template<int S> __device__ __forceinline__ void dft4(float2* a) {
    float2 t0 = cadd(a[0], a[2]), t1 = csub(a[0], a[2]);
    float2 t2 = cadd(a[1], a[3]), t3 = csub(a[1], a[3]);
    a[0] = cadd(t0, t2);
    a[2] = csub(t0, t2);
    a[1] = caddi<S>(t1, t3);
    a[3] = csubi<S>(t1, t3);
}

// ---------- Stockham radix-4 pass on float2 LDS, reg twiddle w1 ----------
// w1f is the FORWARD twiddle (cos, -sin) for this thread's s; S>0 conjugates.
template<int LS, int S>
__device__ __forceinline__ void pass_cx(const float2* src, float2* dst, int t, float2 w1f) {
    float2 a[4];
    #pragma unroll
    for (int r = 0; r < 4; ++r) a[r] = src[PAD(t + r * 256)];
    if (LS > 1) {
        float2 w1 = (S > 0) ? make_float2(w1f.x, -w1f.y) : w1f;
        float2 w2 = cmul(w1, w1);
        float2 w3 = cmul(w2, w1);
        a[1] = cmul(a[1], w1);
        a[2] = cmul(a[2], w2);
        a[3] = cmul(a[3], w3);
    }
    dft4<S>(a);
    int s = t & (LS - 1);
    int base = (t / LS) * (4 * LS) + s;
    #pragma unroll
    for (int r = 0; r < 4; ++r) dst[PAD(base + r * LS)] = a[r];
}

// Forward twiddles for the 4 twiddled passes, computed once per thread (t<256).
struct Tw { float2 t4, t16, t64, t256; };
__device__ __forceinline__ Tw make_tw(int t) {
    Tw w;
    float sn, cs;
    const float c0 = 6.2831853071795864769f;
    __sincosf(c0 * (float)(t & 3)   * (1.0f / 16.0f),   &sn, &cs); w.t4   = make_float2(cs, -sn);
    __sincosf(c0 * (float)(t & 15)  * (1.0f / 64.0f),   &sn, &cs); w.t16  = make_float2(cs, -sn);
    __sincosf(c0 * (float)(t & 63)  * (1.0f / 256.0f),  &sn, &cs); w.t64  = make_float2(cs, -sn);
    __sincosf(c0 * (float)(t & 255) * (1.0f / 1024.0f), &sn, &cs); w.t256 = make_float2(cs, -sn);
    return w;
}

// 1024-pt FFT: input natural order in A, output in B. act = (t < 256).
// Caller must __syncthreads() before calling.
template<int S>
__device__ __forceinline__ void fft1024_cx(float2* A, float2* B, int t, bool act, const Tw& w) {
    if (act) pass_cx<1,   S>(A, B, t, make_float2(1.0f, 0.0f));
    __syncthreads();
    if (act) pass_cx<4,   S>(B, A, t, w.t4);
    __syncthreads();
    if (act) pass_cx<16,  S>(A, B, t, w.t16);
    __syncthreads();
    if (act) pass_cx<64,  S>(B, A, t, w.t64);
    __syncthreads();
    if (act) pass_cx<256, S>(A, B, t, w.t256);
    __syncthreads();
}

// ---------- K_genG_fc0 ----------
// Blocks 0..1023: genG, wave-per-unit. unit u = blk*4 + wave; (l,o,i) from u.
// Each lane owns 16 bins k = lane + 64j. Modes outer, bins inner; imag
// accumulator defers the *omega to the end. Lane 0 handles Nyquist + DC.
// Blocks 1024..1279: fc0 + rfft for row = blk-1024.
__global__ __launch_bounds__(256) void k_genG_fc0(
    const float* __restrict__ pole_re, const float* __restrict__ pole_im,
    const float* __restrict__ res_re,  const float* __restrict__ res_im,
    const float* __restrict__ spec_re, const float* __restrict__ spec_im,
    const float* __restrict__ conv_w,  const float* __restrict__ tgrid,
    const float* __restrict__ x,       const float* __restrict__ fc0_w,
    const float* __restrict__ fc0_b,
    float2* __restrict__ G, float2* __restrict__ alpha)
{
    __shared__ float2 Acx[PADDED_M], Bcx[PADDED_M];
    int t = threadIdx.x;
    int blk = blockIdx.x;
    float dt = tgrid[1] - tgrid[0];
    float fscale = 6.2831853071795864769f / ((float)NFFT * dt);

    if (blk < NLAYER * WW * WW / 4) {
        // ---- genG: one (l,o,i) unit per wave ----
        int lane = t & 63;
        int u = blk * 4 + (t >> 6);
        int l = u >> 10, r = u & 1023, o = r >> 5, i = r & 31;
        int pb = ((l * WW + i) * WW + o) * MM;
        float cw = conv_w[(l * WW + o) * WW + i];
        float w2r[16];
        float2 acc[16];
        #pragma unroll
        for (int j = 0; j < 16; ++j) {
            float wv = fscale * (float)(lane + 64 * j);
            w2r[j] = wv * wv;
            acc[j] = make_float2(cw, 0.0f);
        }
        #pragma unroll
        for (int mq = 0; mq < 4; ++mq) {
            float4 P_re = *(const float4*)&pole_re[pb + 4 * mq];
            float4 P_im = *(const float4*)&pole_im[pb + 4 * mq];
            float4 R_re = *(const float4*)&res_re [pb + 4 * mq];
            float4 R_im = *(const float4*)&res_im [pb + 4 * mq];
            #pragma unroll
            for (int mm = 0; mm < 4; ++mm) {
                float Rp = (&P_re.x)[mm], Ip = (&P_im.x)[mm];
                float Rr = (&R_re.x)[mm], Ir = (&R_im.x)[mm];
                float b   = fmaf(Rr, Rp, Ir * Ip);      // Re(r * conj(p))
                float c   = fmaf(Rp, Rp, Ip * Ip);      // |p|^2
                float dd  = 2.0f * Rp;
                float dd2 = dd * dd;
                float add = Rr * dd;
                float bdd = b * dd;
                #pragma unroll
                for (int j = 0; j < 16; ++j) {
                    float uu  = c - w2r[j];
                    float inv = __builtin_amdgcn_rcpf(fmaf(dd2, w2r[j], uu * uu));
                    acc[j].x = fmaf(fmaf(add, w2r[j], b * uu), -inv, acc[j].x);
                    acc[j].y = fmaf(fmaf(Rr, uu, -bdd), inv, acc[j].y);  // *wv deferred
                }
            }
        }
        #pragma unroll
        for (int j = 0; j < 16; ++j)
            acc[j].y *= fscale * (float)(lane + 64 * j);
        if (lane < MM) {               // spectral-conv fold: bins k = lane < 16
            if (lane) {
                acc[0].x += spec_re[pb + lane];
                acc[0].y += spec_im[pb + lane];
            } else {
                acc[0].x += spec_re[pb];   // DC stays real
            }
        }
        float2* grow = G + (size_t)((l * WW + o) * WW + i) * AST;
        #pragma unroll
        for (int j = 0; j < 16; ++j) grow[lane + 64 * j] = acc[j];
        if (lane == 0) {               // Nyquist: Re(H(w_nyq)), w negative
            float wn = -fscale * (float)M2;
            float accn = cw;
            #pragma unroll
            for (int mq = 0; mq < 4; ++mq) {
                float4 P_re = *(const float4*)&pole_re[pb + 4 * mq];
                float4 P_im = *(const float4*)&pole_im[pb + 4 * mq];
                float4 R_re = *(const float4*)&res_re [pb + 4 * mq];
                float4 R_im = *(const float4*)&res_im [pb + 4 * mq];
                #pragma unroll
                for (int mm = 0; mm < 4; ++mm) {
                    float Rp = (&P_re.x)[mm], Ip = (&P_im.x)[mm];
                    float Rr = (&R_re.x)[mm], Ir = (&R_im.x)[mm];
                    float e   = wn - Ip;
                    float num = fmaf(Ir, e, -(Rr * Rp));
                    float den = fmaf(e, e, Rp * Rp);
                    accn += num * __builtin_amdgcn_rcpf(den);
                }
            }
            grow[M2] = make_float2(accn, 0.0f);
        }
    } else {
        // ---- fc0 + rfft path ----
        int row = blk - NLAYER * WW * WW / 4;   // b*32 + w
        int b = row >> 5, w = row & 31;
        float w0 = fc0_w[2 * w], w1 = fc0_w[2 * w + 1], b0 = fc0_b[w];
        Tw tw = make_tw(t);
        const float2* x2 = (const float2*)(x + (size_t)b * NFFT);
        #pragma unroll
        for (int j = 0; j < 4; ++j) {
            int n = t + j * 256;
            float2 xv = x2[n];
            float g0 = (float)(2 * n)     * (1.0f / 2047.0f);
            float g1 = (float)(2 * n + 1) * (1.0f / 2047.0f);
            float v0 = gelu_f(fmaf(w0, xv.x, fmaf(w1, g0, b0)));
            float v1 = gelu_f(fmaf(w0, xv.y, fmaf(w1, g1, b0)));
            Acx[PAD(n)] = make_float2(v0, v1);   // z[n] = h[2n] + i h[2n+1]
        }
        __syncthreads();
        fft1024_cx<-1>(Acx, Bcx, t, true, tw);
        float2* arow = alpha + (size_t)row * AST;
        #pragma unroll
        for (int j = 0; j < 4; ++j) {
            int k  = t + j * 256;
            int mk = (M2 - k) & (M2 - 1);
            float2 Zk  = Bcx[PAD(k)];
            float2 Zmk = Bcx[PAD(mk)];
            float2 A  = make_float2(0.5f * (Zk.x + Zmk.x), 0.5f * (Zk.y - Zmk.y));
            float2 Bv = make_float2(0.5f * (Zk.y + Zmk.y), -0.5f * (Zk.x - Zmk.x));
            float ph = (3.1415926535897932385f / (float)M2) * (float)k;
            float sn, cs;
            __sincosf(ph, &sn, &cs);
            float2 e = make_float2(cs, -sn);           // e^{-i*2pi*k/N}
            float2 X = cadd(A, cmul(Bv, e));
            arow[k] = X;
            if (k == 0) arow[M2] = make_float2(A.x - Bv.x, 0.0f);
        }
    }
}

// ---------- K_layer: einsum over i + irfft + gelu + (rfft | store h) ----------
// block = (b,o) row, 512 threads. Yh[k] = sum_i alpha[b,i,k]*G[l,o,i,k]
template<bool LAST>
__global__ __launch_bounds__(512) void k_apply_fft(
    const float2* __restrict__ alpha, const float2* __restrict__ G,
    const float* __restrict__ conv_b, float2* __restrict__ alpha_next,
    float2* __restrict__ hout, int layer)
{
    __shared__ __align__(16) float2 Ycx[M2 + 2];
    __shared__ float2 Acx[PADDED_M], Bcx[PADDED_M];
    int t = threadIdx.x;
    int row = blockIdx.x;            // b*32 + o
    int b = row >> 5, o = row & 31;
    const float2* abase = alpha + (size_t)(b * WW) * AST;
    const float2* gbase = G + (size_t)((layer * WW + o) * WW) * AST;
    Tw tw;
    if (t < 256) tw = make_tw(t);

    // einsum: thread t owns bins 2t, 2t+1 -> float4 loads (16B)
    float2 acc0 = make_float2(0.0f, 0.0f);
    float2 acc1 = make_float2(0.0f, 0.0f);
    #pragma unroll 4
    for (int i = 0; i < 32; ++i) {
        const float4* ar = (const float4*)(abase + (size_t)i * AST);
        const float4* gr = (const float4*)(gbase + (size_t)i * AST);
        float4 av = ar[t];
        float4 gv = gr[t];
        acc0.x = fmaf(av.x, gv.x, fmaf(-av.y, gv.y, acc0.x));
        acc0.y = fmaf(av.x, gv.y, fmaf( av.y, gv.x, acc0.y));
        acc1.x = fmaf(av.z, gv.z, fmaf(-av.w, gv.w, acc1.x));
        acc1.y = fmaf(av.z, gv.w, fmaf( av.w, gv.z, acc1.y));
    }
    // Nyquist: real dot over i, wave-0 shuffle reduce
    if (t < 64) {
        float p = 0.0f;
        if (t < 32)
            p = abase[(size_t)t * AST + M2].x * gbase[(size_t)t * AST + M2].x;
        #pragma unroll
        for (int off = 16; off >= 1; off >>= 1) p += __shfl_xor(p, off);
        if (t == 0) Ycx[M2] = make_float2(p, 0.0f);
    }
    if (t == 0) acc0.x += (float)NFFT * conv_b[layer * WW + o];
    ((float4*)Ycx)[t] = make_float4(acc0.x, acc0.y, acc1.x, acc1.y);
    __syncthreads();

    // irfft pack: Z[k] = A + iB from X[k], X[M2-k]
    #pragma unroll
    for (int j = 0; j < 2; ++j) {
        int k = t + j * 512;
        float2 Xk = Ycx[k];
        float2 Xm = Ycx[M2 - k];
        float2 A = make_float2(0.5f * (Xk.x + Xm.x), 0.5f * (Xk.y - Xm.y));
        float2 u = make_float2(Xk.x - Xm.x, Xk.y + Xm.y);
        float ph = (3.1415926535897932385f / (float)M2) * (float)k;
        float sn, cs;
        __sincosf(ph, &sn, &cs);
        float2 e = make_float2(cs, sn);            // e^{+i*2pi*k/N}
        float2 Bv = cmul(u, e);
        Acx[PAD(k)] = make_float2(A.x - 0.5f * Bv.y, A.y + 0.5f * Bv.x);
    }
    __syncthreads();
    fft1024_cx<1>(Acx, Bcx, t, t < 256, tw);      // inverse -> B
    const float invM = 1.0f / (float)M2;
    if (LAST) {
        #pragma unroll
        for (int j = 0; j < 2; ++j) {
            int n = t + j * 512;
            float2 z = Bcx[PAD(n)];
            hout[(size_t)row * M2 + n] = make_float2(gelu_f(z.x * invM), gelu_f(z.y * invM));
        }
    } else {
        #pragma unroll
        for (int j = 0; j < 2; ++j) {
            int n = t + j * 512;
            float2 z = Bcx[PAD(n)];
            Acx[PAD(n)] = make_float2(gelu_f(z.x * invM), gelu_f(z.y * invM));
        }
        __syncthreads();
        fft1024_cx<-1>(Acx, Bcx, t, t < 256, tw);
        float2* arow = alpha_next + (size_t)row * AST;
        #pragma unroll
        for (int j = 0; j < 2; ++j) {
            int k  = t + j * 512;
            int mk = (M2 - k) & (M2 - 1);
            float2 Zk  = Bcx[PAD(k)];
            float2 Zmk = Bcx[PAD(mk)];
            float2 A  = make_float2(0.5f * (Zk.x + Zmk.x), 0.5f * (Zk.y - Zmk.y));
            float2 Bv = make_float2(0.5f * (Zk.y + Zmk.y), -0.5f * (Zk.x - Zmk.x));
            float ph = (3.1415926535897932385f / (float)M2) * (float)k;
            float sn, cs;
            __sincosf(ph, &sn, &cs);
            float2 e = make_float2(cs, -sn);       // e^{-i*2pi*k/N}
            float2 X = cadd(A, cmul(Bv, e));
            arow[k] = X;
            if (k == 0) arow[M2] = make_float2(A.x - Bv.x, 0.0f);
        }
    }
}

// ---------- K5: head ----------
__global__ __launch_bounds__(256) void k_head(
    const float* __restrict__ h, const float* __restrict__ fc1_w,
    const float* __restrict__ fc1_b, const float* __restrict__ fc2_w,
    const float* __restrict__ fc2_b, float* __restrict__ out)
{
    __shared__ float s_w1[128 * 32];
    __shared__ float s_b1[128];
    __shared__ float s_w2[128];
    __shared__ float s_part[4][64];
    int t = threadIdx.x;
    for (int j = t; j < 128 * 32; j += 256) s_w1[j] = fc1_w[j];
    if (t < 128) { s_b1[t] = fc1_b[t]; s_w2[t] = fc2_w[t]; }
    __syncthreads();
    int wv  = t >> 6;                       // wave id = n-group
    int ln  = t & 63;
    int pos = blockIdx.x * 64 + ln;         // b*2048 + l
    int b = pos >> LOG2N, l = pos & (NFFT - 1);
    float hreg[32];
    #pragma unroll
    for (int w = 0; w < 32; ++w) hreg[w] = h[(b * WW + w) * NFFT + l];
    float acc = 0.0f;
    int n0 = wv * 32;
    for (int n = n0; n < n0 + 32; ++n) {
        float a = s_b1[n];
        #pragma unroll
        for (int w = 0; w < 32; w += 4) {
            float4 ww = *(const float4*)&s_w1[n * 32 + w];
            a = fmaf(ww.x, hreg[w],     a);
            a = fmaf(ww.y, hreg[w + 1], a);
            a = fmaf(ww.z, hreg[w + 2], a);
            a = fmaf(ww.w, hreg[w + 3], a);
        }
        acc = fmaf(s_w2[n], gelu_f(a), acc);
    }
    s_part[wv][ln] = acc;
    __syncthreads();
    if (t < 64) {
        float r = s_part[0][t] + s_part[1][t] + s_part[2][t] + s_part[3][t] + fc2_b[0];
        out[blockIdx.x * 64 + t] = r;
    }
}

extern "C" void kernel_launch(void* const* d_in, const int* in_sizes, int n_in,
                              void* d_out, int out_size, void* d_ws, size_t ws_size,
                              hipStream_t stream)
{
    const float* x       = (const float*)d_in[0];
    const float* tg      = (const float*)d_in[1];
    const float* fc0_w   = (const float*)d_in[2];
    const float* fc0_b   = (const float*)d_in[3];
    const float* pole_re = (const float*)d_in[4];
    const float* pole_im = (const float*)d_in[5];
    const float* res_re  = (const float*)d_in[6];
    const float* res_im  = (const float*)d_in[7];
    const float* spec_re = (const float*)d_in[8];
    const float* spec_im = (const float*)d_in[9];
    const float* conv_w  = (const float*)d_in[10];
    const float* conv_b  = (const float*)d_in[11];
    const float* fc1_w   = (const float*)d_in[12];
    const float* fc1_b   = (const float*)d_in[13];
    const float* fc2_w   = (const float*)d_in[14];
    const float* fc2_b   = (const float*)d_in[15];
    float* out = (float*)d_out;

    char* ws = (char*)d_ws;
    const size_t plane = (size_t)(BB * WW) * AST * sizeof(float2);   // 2.11 MiB
    float2* alphaA = (float2*)ws;
    float2* alphaB = (float2*)(ws + plane);
    float2* hbuf   = (float2*)(ws + 2 * plane);                      // 2 MiB
    float2* Gbuf   = (float2*)(ws + 3 * plane);

    hipLaunchKernelGGL(k_genG_fc0, dim3(NLAYER * WW * WW / 4 + BB * WW), dim3(256), 0, stream,
                       pole_re, pole_im, res_re, res_im, spec_re, spec_im,
                       conv_w, tg, x, fc0_w, fc0_b, Gbuf, alphaA);
    float2* acur = alphaA;
    float2* anxt = alphaB;
    for (int layer = 0; layer < NLAYER; ++layer) {
        if (layer < NLAYER - 1)
            hipLaunchKernelGGL((k_apply_fft<false>), dim3(BB * WW), dim3(512), 0, stream,
                               acur, Gbuf, conv_b, anxt, (float2*)nullptr, layer);
        else
            hipLaunchKernelGGL((k_apply_fft<true>), dim3(BB * WW), dim3(512), 0, stream,
                               acur, Gbuf, conv_b, (float2*)nullptr, hbuf, layer);
        float2* tmp = acur; acur = anxt; anxt = tmp;
    }
    hipLaunchKernelGGL(k_head, dim3(BB * NFFT / 64), dim3(256), 0, stream,
                       (const float*)hbuf, fc1_w, fc1_b, fc2_w, fc2_b, out);
}